// Round 8
// baseline (95.480 us; speedup 1.0000x reference)
//
#include <hip/hip_runtime.h>
#include <cstdint>

// Problem constants: view1 (B=8, C=4, H=256, W=256) fp32, F 3x3 fp32.
constexpr int Hh = 256, Ww = 256, BCc = 32;
// T4[u(264)][rblk(35)][ch(32)][rw(8)] fp16. ridx = r+8: blk0 = rows -8..-1
// (zero), blk1..32 = rows 0..255, blk33/34 = rows 256..271 (zero). Planes
// u=256..263 fully zero. Strides (bytes): u: 17920, rblk: 512, ch: 16.
constexpr int RBLK = 35;
constexpr int USTRIDE = RBLK * BCc * 8 * 2;    // 17920 B
constexpr int UPLANES = 264;

typedef _Float16 half2v   __attribute__((ext_vector_type(2)));
typedef _Float16 half8v   __attribute__((ext_vector_type(8)));
typedef __fp16   fp16x2   __attribute__((ext_vector_type(2)));
typedef float    float16v __attribute__((ext_vector_type(16)));
typedef uint32_t uint4v   __attribute__((ext_vector_type(4)));

static __device__ inline half2v pack2(float a, float b) {
    fp16x2 r = __builtin_amdgcn_cvt_pkrtz(a, b);
    return __builtin_bit_cast(half2v, r);
}

// ---------------------------------------------------------------------------
// Pack view1 (ch,H,W) f32 -> T4 fp16. Blocks 0..511: (chg 4) x (rblk 32) x
// (utile 4, 64 u): 8ch x 8r x 64u each, single pass; write side is 128B-
// contiguous (8 ch x 16 B). Blocks 512..519: grid-stride zero of pads.
// ---------------------------------------------------------------------------
__global__ __launch_bounds__(256) void fume_pack(const float* __restrict__ in,
                                                 char* __restrict__ T4) {
    const int t   = threadIdx.x;
    const int bid = blockIdx.x;
    if (bid >= 512) {                           // zero pads
        constexpr int NA = UPLANES * 3 * 32;    // blk{0,33,34} x u x ch
        constexpr int NB = 8 * 32 * 32;         // u 256..263 x blk1..32 x ch
        for (int id = (bid - 512) * 256 + t; id < NA + NB; id += 8 * 256) {
            int u, blk, ch;
            if (id < NA) {
                u = id / 96;
                int rem = id - u * 96;
                int bsel = rem >> 5;
                blk = (bsel == 0) ? 0 : (bsel == 1 ? 33 : 34);
                ch = rem & 31;
            } else {
                int id2 = id - NA;
                u = 256 + (id2 >> 10);
                int rem = id2 & 1023;
                blk = 1 + (rem >> 5);
                ch = rem & 31;
            }
            uint4v z = {0, 0, 0, 0};
            *(uint4v*)(T4 + (size_t)u * USTRIDE + blk * 512 + ch * 16) = z;
        }
        return;
    }
    __shared__ float lds[8][8][65];             // [ch][r][u(+pad)]
    const int chg = bid & 3;
    const int r0  = ((bid >> 2) & 31) * 8;      // one rblk
    const int u0  = (bid >> 7) * 64;
    const int blk = (r0 >> 3) + 1;              // ridx = r+8

#pragma unroll
    for (int it = 0; it < 16; ++it) {           // 8ch x 8r x 64u coalesced
        int idx = it * 256 + t;
        int ch = idx >> 9, rr = (idx >> 6) & 7, uu = idx & 63;
        lds[ch][rr][uu] =
            in[(chg * 8 + ch) * (Hh * Ww) + (r0 + rr) * Ww + u0 + uu];
    }
    __syncthreads();
    const int chl = t & 7;
#pragma unroll
    for (int p = 0; p < 2; ++p) {
        int u_l = (t >> 3) + p * 32;            // 0..63
        uint32_t w[4];
#pragma unroll
        for (int j = 0; j < 4; ++j) {
            half2v pr = pack2(lds[chl][2 * j][u_l], lds[chl][2 * j + 1][u_l]);
            __builtin_memcpy(&w[j], &pr, 4);
        }
        uint4v val = {w[0], w[1], w[2], w[3]};
        *(uint4v*)(T4 + (size_t)(u0 + u_l) * USTRIDE + blk * 512
                   + (chg * 8 + chl) * 16) = val;
    }
}

// ---------------------------------------------------------------------------
// MFMA main (R22 = R21 + stride-4 chunk INTERLEAVE across the 4 waves).
// Strip = 32 px at row y; one 32x32x16 MFMA per u:
//   A[m=px][k] = tent(vidx_px(u) - (8*(M_u+h) + j)),  k = h*8+j, h=lane>>5
//   B[k][ch=n] = T4[u][M_u+h][ch][j] -> one dwordx4/lane; the wave's 64
//                loads are 1 KB CONTIGUOUS (2 rblks x 32ch x 16B)
//   D[m][n]: col=lane&31(=ch), row=(reg&3)+8*(reg>>2)+4*h (guide-verified)
// M_u per u (coverage needs strip-spread < 6; 32-px span <= 5.69, margin
// 0.31). Final chunk overruns <= hi+3 <= 258 < 264 into zeroed u-planes,
// tents mask (double-masked).
// History: R15 lane-parallel window precompute + readlane + scalar-base
// addressing. R16 (REVERTED) depth-3 branchy ring. R17 XCD y-band swizzle:
// kept. R18 tent trim: -2.7us. R19 (REVERTED) 16-px strips. R20 (REVERTED)
// half-split+atomics. R21 depth-2 straight-line pipeline: kept (neutral
// alone). R22 THEORY: per-wave u-step wall time ~1400 cyc vs ~40 issue ->
// L2-MISS bound. Cause: the R14 quarter-split starts the block's 4 waves at
// u ~ {0,64,128,192}, so every XCD touches ALL of T4 (4.7MB > 4MB L2) at
// all times -> cyclic LRU thrash, ~all loads served by L3 (~600-900 cyc,
// ~13.8 TB/s aggregate = near IC wall). Fix: wave wq takes chunks
// {wq, wq+4, wq+8,...} -> all 4 waves stay within ~16 u of each other;
// with the y-band swizzle the whole XCD sweeps a ~600KB moving window ->
// L2 hits (~200 cyc), fully hidden by the retained depth-2 buffer.
// Windows per u are BITWISE identical (same integer u -> same Mf); chunk
// partition is exact (nit = (C+3-wq)>>2, verified C=2,5,64); per-chunk vh
// recompute (1 fmaf) removes the serial cross-chunk vh chain.
// ---------------------------------------------------------------------------
__global__ __launch_bounds__(256, 4) void fume_mfma(const char* __restrict__ T4,
                                                    const float* __restrict__ Fm,
                                                    float* __restrict__ out) {
    __shared__ float red[4][32][33];
    const int t    = threadIdx.x;
    const int lane = t & 63;
    const int wq   = t >> 6;                    // wave index 0..3
    const int px   = lane & 31;                 // pixel (A.m) and channel (B.n)
    const int h    = lane >> 5;                 // k-half: window rows 8h..8h+7
    // XCD swizzle: xcd = bid&7 owns y-band [32k,32k+32); idx8>>3 = y-in-band,
    // idx8&7 = x0 tile.
    const int bid  = (int)blockIdx.x;
    const int idx8 = bid >> 3;
    const int y    = ((bid & 7) << 5) + (idx8 >> 3);
    const int x0   = (idx8 & 7) * 32;
    const int x    = x0 + px;

    // Own-pixel epipolar line (reference op order).
    float xf = (float)x, yf = (float)y;
    float a = Fm[0] * xf + Fm[3] * yf + Fm[6];
    float b = Fm[1] * xf + Fm[4] * yf + Fm[7];
    float c = Fm[2] * xf + Fm[5] * yf + Fm[8];
    float n = sqrtf(a * a + b * b) + 1e-12f;
    a /= n; b /= n; c /= n;

    float alpha, beta_i;                        // vidx(u) = alpha*u + beta_i
    int u_lo, u_hi;
    if (fabsf(b) > 1e-6f) {
        alpha  = -a / b;
        beta_i = -c / b + 8.f;                  // vidx = v + 8
        u_lo = 0; u_hi = Ww - 1;
        if (fabsf(alpha) > 1e-12f) {
            float inv = 1.f / alpha;
            float t0 = (7.f - beta_i) * inv;    // v = -1
            float t1 = (264.f - beta_i) * inv;  // v = 256
            int lo = (int)floorf(fminf(t0, t1));
            int hi = (int)ceilf (fmaxf(t0, t1));
            u_lo = lo > 0 ? lo : 0;
            u_hi = hi < (Ww - 1) ? hi : (Ww - 1);
        } else if (beta_i <= 7.f || beta_i >= 264.f) {
            u_lo = 1 << 20; u_hi = -(1 << 20);
        }
    } else {                                    // 'ok'=false: contributes 0
        alpha = 0.f; beta_i = 3.0e4f;           // tents saturate to 0
        u_lo = 1 << 20; u_hi = -(1 << 20);
    }

    // Strip-corner lines (x0, x0+31) for the per-u window base (v monotone
    // in x for this F family; corner x-set is a subset of R12's passing set).
    float xA = (float)x0, xB = (float)(x0 + 31);
    float aA = Fm[0] * xA + Fm[3] * yf + Fm[6];
    float bA = Fm[1] * xA + Fm[4] * yf + Fm[7];
    float cA = Fm[2] * xA + Fm[5] * yf + Fm[8];
    float aB = Fm[0] * xB + Fm[3] * yf + Fm[6];
    float bB = Fm[1] * xB + Fm[4] * yf + Fm[7];
    float cB = Fm[2] * xB + Fm[5] * yf + Fm[8];
    float alA = -aA / bA, beA = -cA / bA + 8.f;
    float alB = -aB / bB, beB = -cB / bB + 8.f;

    // Wave-union of clip windows -> uniform scalar bounds (same for all 4
    // waves: same 32 pixels).
    int lo = u_lo, hi = u_hi;
#pragma unroll
    for (int off = 1; off < 64; off <<= 1) {
        int l2 = __shfl_xor(lo, off, 64);
        int h2 = __shfl_xor(hi, off, 64);
        lo = lo < l2 ? lo : l2;
        hi = hi > h2 ? hi : h2;
    }
    lo = __builtin_amdgcn_readfirstlane(lo);
    hi = __builtin_amdgcn_readfirstlane(hi);

    float16v acc = {0.f, 0.f, 0.f, 0.f, 0.f, 0.f, 0.f, 0.f,
                    0.f, 0.f, 0.f, 0.f, 0.f, 0.f, 0.f, 0.f};

    if (lo <= hi) {
        int len = hi - lo + 1;
        int C   = (len + 3) >> 2;               // total 4-u chunks
        // Stride-4 interleave: wave wq owns chunks {wq, wq+4, ...} < C.
        int nit = (C + 3 - wq) >> 2;            // exact count; 0 when C<=wq
        if (nit < 0) nit = 0;
        int us0 = lo + wq * 4;                  // first u of first chunk

        // Lane-parallel window precompute: lane l -> window for
        // u(l) = us0 + 16*(l>>2) + (l&3)  (chunk l>>2, sub l&3), so the
        // in-loop readlane index stays 4*chunk + i. Same op order as R14.
        int   u_l = us0 + ((lane >> 2) << 4) + (lane & 3);
        float uf  = (float)u_l;
        float vAl = fmaf(alA, uf, beA);
        float vBl = fmaf(alB, uf, beB);
        float mnu = fminf(vAl, vBl);
        float Mf  = floorf(fmaf(mnu, 0.125f, -0.125f));  // floor((mn-1)/8)
        Mf = fmaxf(0.f, fminf(Mf, 33.f));
        int   vMo  = (int)Mf << 9;              // rblk byte offset
        float vB8f = Mf * 8.f;                  // exact (<= 264)
        int   vB8i = __builtin_bit_cast(int, vB8f);

        float l8h = (float)(8 * h);
        float u0f = (float)us0;
        const char* pb0 = T4 + (size_t)us0 * USTRIDE;
        const int voff  = (h << 9) + (px << 4); // per-lane constant

        const half2v one2 = {(_Float16)1.f, (_Float16)1.f};

        uint4v b0[4], b1[4];

        // Issue the 4 B loads of this wave's chunk CH (u = us0+16*CH+i).
#define FUME_ISS(BUF, CH)                                                     \
    do {                                                                      \
        const char* pck_ = pb0 + (size_t)(CH) * (16 * USTRIDE);               \
        const int rb_ = (CH) * 4;                                             \
        _Pragma("unroll")                                                     \
        for (int i_ = 0; i_ < 4; ++i_) {                                      \
            int Mo_ = __builtin_amdgcn_readlane(vMo, rb_ + i_);               \
            (BUF)[i_] = *(const uint4v*)(pck_ + (size_t)i_ * USTRIDE          \
                                         + (size_t)Mo_ + voff);               \
        }                                                                     \
    } while (0)

        // Compute chunk CH from BUF; vh recomputed fresh per chunk (no
        // cross-chunk serial dependency).
#define FUME_COMP(BUF, CH)                                                    \
    do {                                                                      \
        const int rb_ = (CH) * 4;                                             \
        float vh_ = fmaf(alpha, u0f + (float)((CH) * 16), beta_i) - l8h;      \
        _Pragma("unroll")                                                     \
        for (int i_ = 0; i_ < 4; ++i_) {                                      \
            float b8_ = __builtin_bit_cast(                                   \
                float, __builtin_amdgcn_readlane(vB8i, rb_ + i_));            \
            float vbl_ = vh_ - b8_;                                           \
            half2v vb2_ = pack2(vbl_, vbl_);                                  \
            uint32_t aw_[4];                                                  \
            _Pragma("unroll")                                                 \
            for (int j_ = 0; j_ < 4; ++j_) {                                  \
                half2v cj_ = {(_Float16)(float)(2 * j_),                      \
                              (_Float16)(float)(2 * j_ + 1)};                 \
                half2v d_  = vb2_ - cj_;                                      \
                uint32_t du_;                                                 \
                __builtin_memcpy(&du_, &d_, 4);                               \
                du_ &= 0x7fff7fffu;                                           \
                half2v ad_;                                                   \
                __builtin_memcpy(&ad_, &du_, 4);                              \
                half2v tj_;                                                   \
                asm("v_pk_add_f16 %0, %1, %2 neg_lo:[0,1] neg_hi:[0,1] clamp" \
                    : "=v"(tj_)                                               \
                    : "v"(one2), "v"(ad_));                                   \
                __builtin_memcpy(&aw_[j_], &tj_, 4);                          \
            }                                                                 \
            half8v A_;                                                        \
            __builtin_memcpy(&A_, aw_, 16);                                   \
            half8v B_ = __builtin_bit_cast(half8v, (BUF)[i_]);                \
            acc = __builtin_amdgcn_mfma_f32_32x32x16_f16(A_, B_, acc, 0, 0, 0);\
            vh_ += alpha;                                                     \
        }                                                                     \
    } while (0)

        if (nit > 0) {
            FUME_ISS(b0, 0);
            int cc = 0;
            // Pair-unrolled steady loop: prefetch ALWAYS issued (clamped
            // chunk index) so the issue pattern is static -> counted vmcnt.
            while (cc + 2 <= nit) {
                FUME_ISS(b1, cc + 1);
                FUME_COMP(b0, cc);              // waits its own 4 (vmcnt 4)
                int pf = (cc + 2 < nit) ? cc + 2 : nit - 1;
                FUME_ISS(b0, pf);
                FUME_COMP(b1, cc + 1);          // waits its own 4 (vmcnt 4)
                cc += 2;
            }
            if (cc < nit) FUME_COMP(b0, cc);    // odd tail: b0 holds chunk cc
        }
#undef FUME_ISS
#undef FUME_COMP
    }

    // Combine the 4 wave partials via LDS; D row = pixel, col(lane) = channel.
#pragma unroll
    for (int r = 0; r < 16; ++r) {
        int m = (r & 3) + 8 * (r >> 2) + 4 * h;   // pixel index 0..31
        red[wq][m][px] = acc[r];                  // [m][ch]
    }
    __syncthreads();
    {
        int pxs = t & 31, cg = t >> 5;            // pixel, ch-group
#pragma unroll
        for (int jj = 0; jj < 4; ++jj) {
            int ch = cg + 8 * jj;
            float val = red[0][pxs][ch] + red[1][pxs][ch]
                      + red[2][pxs][ch] + red[3][pxs][ch];
            out[(size_t)ch * (Hh * Ww) + y * Ww + x0 + pxs] = val;
        }
    }
}

// ---------------------------------------------------------------------------
// Fallback (ws too small): R1-style masked scalar path.
// ---------------------------------------------------------------------------
__global__ __launch_bounds__(256) void fume_fallback(const float* __restrict__ src,
                                                     const float* __restrict__ Fm,
                                                     float* __restrict__ out) {
    int g = blockIdx.x * 256 + threadIdx.x;
    int part = g & 3;
    int pix  = g >> 2;
    int x = pix & (Ww - 1);
    int y = pix >> 8;
    int ch0 = part * 8;
    float xf = (float)x, yf = (float)y;
    float a = Fm[0] * xf + Fm[3] * yf + Fm[6];
    float b = Fm[1] * xf + Fm[4] * yf + Fm[7];
    float c = Fm[2] * xf + Fm[5] * yf + Fm[8];
    float n = sqrtf(a * a + b * b) + 1e-12f;
    a /= n; b /= n; c /= n;
    float acc[8];
#pragma unroll
    for (int k = 0; k < 8; ++k) acc[k] = 0.f;
    if (fabsf(b) > 1e-6f) {
        float alpha = -a / b, beta = -c / b;
        for (int u = 0; u < Ww; ++u) {
            float v  = fmaf(alpha, (float)u, beta);
            float rf = floorf(v);
            float f  = v - rf;
            int   ri = (int)rf;
            float w0 = ((unsigned)ri       < (unsigned)Hh) ? (1.f - f) : 0.f;
            float w1 = ((unsigned)(ri + 1) < (unsigned)Hh) ? f         : 0.f;
            int r0 = ri < 0 ? 0 : (ri > Hh - 1 ? Hh - 1 : ri);
            int r1 = ri + 1 < 0 ? 0 : (ri + 1 > Hh - 1 ? Hh - 1 : ri + 1);
#pragma unroll
            for (int k = 0; k < 8; ++k) {
                float s0 = src[(size_t)(ch0 + k) * (Hh * Ww) + r0 * Ww + u];
                float s1 = src[(size_t)(ch0 + k) * (Hh * Ww) + r1 * Ww + u];
                acc[k] = fmaf(w0, s0, fmaf(w1, s1, acc[k]));
            }
        }
    }
#pragma unroll
    for (int k = 0; k < 8; ++k)
        out[(size_t)(ch0 + k) * (Hh * Ww) + pix] = acc[k];
}

extern "C" void kernel_launch(void* const* d_in, const int* in_sizes, int n_in,
                              void* d_out, int out_size, void* d_ws, size_t ws_size,
                              hipStream_t stream) {
    const float* view1 = (const float*)d_in[0];
    const float* Fm    = (const float*)d_in[1];
    float* out = (float*)d_out;

    constexpr size_t t4_bytes = (size_t)UPLANES * USTRIDE;   // ~4.7 MB
    if (ws_size >= t4_bytes) {
        char* T4 = (char*)d_ws;
        fume_pack<<<520, 256, 0, stream>>>(view1, T4);
        fume_mfma<<<2048, 256, 0, stream>>>(T4, Fm, out);
    } else {
        fume_fallback<<<(Hh * Ww * 4) / 256, 256, 0, stream>>>(view1, Fm, out);
    }
}